// Round 6
// baseline (306.148 us; speedup 1.0000x reference)
//
#include <hip/hip_runtime.h>

// ---------------------------------------------------------------------------
// QuadraticSplineLayer on MI355X (gfx950)
// reduce(mean/std) -> pack xs/w1/w2 (fp16 swizzled LDS-image blocks)
//   -> GEMM1 (K-split) -> pack_h -> GEMM2+spline epilogue (71KB LDS +
//   launch_bounds(512,2) => 2 blocks/CU to hide per-K-step vmcnt drain)
//   -> log-density combine.
// ---------------------------------------------------------------------------

typedef _Float16 f16x8 __attribute__((ext_vector_type(8)));
typedef float    f32x4 __attribute__((ext_vector_type(4)));
typedef unsigned short us8 __attribute__((ext_vector_type(8)));

#define EPS_C   1e-6f
#define INV_PI  0.3183098861837907f
#define SEPI    274                               // padded epi row stride (floats)

__device__ __forceinline__ unsigned short f2h(float f) {
  _Float16 h = (_Float16)f;
  return __builtin_bit_cast(unsigned short, h);
}

__device__ __forceinline__ float fast_tanh(float x) {
  float xc = fminf(fmaxf(x, -15.f), 15.f);
  float p = __expf(2.f * xc);
  return (p - 1.f) * __builtin_amdgcn_rcpf(p + 1.f);
}

__device__ __forceinline__ void gld16(const void* g, void* l) {
  __builtin_amdgcn_global_load_lds(
      (const __attribute__((address_space(1))) unsigned int*)g,
      (__attribute__((address_space(3))) unsigned int*)l, 16, 0, 0);
}

// ---------------- reduction: global mean / rstd of x_passive ---------------

__global__ void k_reduce1(const float* __restrict__ xp, float* __restrict__ part) {
  int tid = threadIdx.x;
  size_t base = (size_t)blockIdx.x * 2048 + (size_t)tid * 8;
  f32x4 v0 = *(const f32x4*)(xp + base);
  f32x4 v1 = *(const f32x4*)(xp + base + 4);
  float s = 0.f, q = 0.f;
#pragma unroll
  for (int j = 0; j < 4; ++j) { s += v0[j] + v1[j]; q += v0[j]*v0[j] + v1[j]*v1[j]; }
#pragma unroll
  for (int o = 32; o; o >>= 1) { s += __shfl_down(s, o); q += __shfl_down(q, o); }
  __shared__ float ls[8];
  int wid = tid >> 6, l = tid & 63;
  if (l == 0) { ls[wid] = s; ls[wid + 4] = q; }
  __syncthreads();
  if (tid == 0) {
    part[blockIdx.x * 2]     = ls[0] + ls[1] + ls[2] + ls[3];
    part[blockIdx.x * 2 + 1] = ls[4] + ls[5] + ls[6] + ls[7];
  }
}

__global__ void k_reduce2(const float* __restrict__ part, float* __restrict__ ms) {
  int tid = threadIdx.x;
  double s = 0.0, q = 0.0;
  for (int i = tid; i < 2048; i += 256) { s += part[2*i]; q += part[2*i+1]; }
#pragma unroll
  for (int o = 32; o; o >>= 1) { s += __shfl_down(s, o); q += __shfl_down(q, o); }
  __shared__ double sd[8];
  if ((tid & 63) == 0) { sd[(tid>>6)*2] = s; sd[(tid>>6)*2+1] = q; }
  __syncthreads();
  if (tid == 0) {
    double S = sd[0]+sd[2]+sd[4]+sd[6], Q = sd[1]+sd[3]+sd[5]+sd[7];
    double N = 4194304.0;
    double mean = S / N;
    double var  = (Q - S*S/N) / (N - 1.0);
    ms[0] = (float)mean;
    ms[1] = (float)(1.0 / sqrt(var));
  }
}

// ---------------- packing kernels (fp16, swizzled LDS-image blocks) --------

__global__ void k_pack_xs(const float* __restrict__ xp, const float* __restrict__ ms,
                          unsigned short* __restrict__ xsp) {
  int b = blockIdx.x, c = threadIdx.x;
  float mean = ms[0], rstd = ms[1];
  const f32x4* src = (const f32x4*)(xp + (size_t)b * 2048 + c * 8);
  f32x4 v0 = src[0], v1 = src[1];
  us8 o;
#pragma unroll
  for (int j = 0; j < 4; ++j) {
    o[j]     = f2h((v0[j] - mean) * rstd);
    o[4 + j] = f2h((v1[j] - mean) * rstd);
  }
  char* dst = (char*)xsp + ((size_t)(b >> 6) * 64 + (c >> 2)) * 4096
            + (b & 63) * 64 + (((c & 3) ^ ((b >> 1) & 3)) * 16);
  *(us8*)dst = o;
}

__global__ void k_pack_w1(const float* __restrict__ w1, unsigned short* __restrict__ w1p) {
  int colg = blockIdx.x * 256 + threadIdx.x;
  int kt = blockIdx.y;
  const float* src = w1 + (size_t)kt * 32 * 1024 + colg;
  float v[32];
#pragma unroll
  for (int kk = 0; kk < 32; ++kk) v[kk] = src[(size_t)kk * 1024];
  int col = colg & 127;
  char* base = (char*)w1p + ((size_t)(colg >> 7) * 64 + kt) * 8192 + col * 64;
#pragma unroll
  for (int c = 0; c < 4; ++c) {
    us8 o;
#pragma unroll
    for (int j = 0; j < 8; ++j) o[j] = f2h(v[c * 8 + j]);
    *(us8*)(base + ((c ^ ((col >> 1) & 3)) * 16)) = o;
  }
}

__global__ void k_pack_w2(const float* __restrict__ w2, unsigned short* __restrict__ w2p) {
  int colg = blockIdx.x * 256 + threadIdx.x;
  int kt = blockIdx.y;
  const float* src = w2 + (size_t)kt * 32 * 34816 + colg;
  float v[32];
#pragma unroll
  for (int kk = 0; kk < 32; ++kk) v[kk] = src[(size_t)kk * 34816];
  int ntile = colg / 272;
  int col = colg - ntile * 272;
  char* base = (char*)w2p + ((size_t)ntile * 32 + kt) * 17408 + col * 64;
#pragma unroll
  for (int c = 0; c < 4; ++c) {
    us8 o;
#pragma unroll
    for (int j = 0; j < 8; ++j) o[j] = f2h(v[c * 8 + j]);
    *(us8*)(base + ((c ^ ((col >> 1) & 3)) * 16)) = o;
  }
}

// ---------------- GEMM1: h_part[ks] = xs @ w1 (K-split, f32 partials) ------

__global__ __launch_bounds__(256) void k_gemm1(const unsigned short* __restrict__ xsp,
                                               const unsigned short* __restrict__ w1p,
                                               float* __restrict__ hpart) {
  __shared__ char sm[2 * 16384];
  int tid = threadIdx.x, wid = tid >> 6, l = tid & 63;
  int cl = l & 15, kq = l >> 4;
  int mt = blockIdx.x, nt = blockIdx.y, ks = blockIdx.z;
  int wr = wid >> 1, wc = wid & 1;

  const char* Ab = (const char*)xsp + ((size_t)(mt * 2) * 64 + ks * 16) * 4096;
  const char* Bb = (const char*)w1p + ((size_t)nt * 64 + ks * 16) * 8192;

  f32x4 acc[4][4] = {};

  auto stage = [&](int i, int buf) {
    char* sA = sm + buf * 16384;
    char* sB = sA + 8192;
    const char* a0 = Ab + (size_t)i * 4096;
    gld16(a0 + tid * 16, sA + tid * 16);
    gld16(a0 + 64 * 4096 + tid * 16, sA + 4096 + tid * 16);
    const char* b0 = Bb + (size_t)i * 8192;
    gld16(b0 + tid * 16, sB + tid * 16);
    gld16(b0 + 4096 + tid * 16, sB + 4096 + tid * 16);
  };

  stage(0, 0);
  __syncthreads();

  int swz = (kq * 16) ^ (((cl >> 1) & 3) << 4);
  int aoff0 = wr * 4096 + cl * 64 + swz;
  int boff0 = (wc * 64 + cl) * 64 + swz;

  for (int i = 0; i < 16; ++i) {
    if (i + 1 < 16) stage(i + 1, (i + 1) & 1);
    const char* sA = sm + (i & 1) * 16384;
    const char* sB = sA + 8192;
    f16x8 a[4], b[4];
#pragma unroll
    for (int rf = 0; rf < 4; ++rf) a[rf] = *(const f16x8*)(sA + aoff0 + rf * 1024);
#pragma unroll
    for (int cf = 0; cf < 4; ++cf) b[cf] = *(const f16x8*)(sB + boff0 + cf * 1024);
#pragma unroll
    for (int rf = 0; rf < 4; ++rf)
#pragma unroll
      for (int cf = 0; cf < 4; ++cf)
        acc[rf][cf] = __builtin_amdgcn_mfma_f32_16x16x32_f16(a[rf], b[cf], acc[rf][cf], 0, 0, 0);
    __syncthreads();
  }

  float* dst = hpart + (size_t)ks * 2048 * 1024;
#pragma unroll
  for (int rf = 0; rf < 4; ++rf)
#pragma unroll
    for (int cf = 0; cf < 4; ++cf)
#pragma unroll
      for (int ri = 0; ri < 4; ++ri) {
        int row = mt * 128 + wr * 64 + rf * 16 + kq * 4 + ri;
        int col = nt * 128 + wc * 64 + cf * 16 + cl;
        dst[(size_t)row * 1024 + col] = acc[rf][cf][ri];
      }
}

// ---------------- pack_h: sum K-split partials, +b1, tanh, fp16 pack -------

__global__ void k_pack_h(const float* __restrict__ hpart, const float* __restrict__ b1,
                         unsigned short* __restrict__ hp) {
  int id = blockIdx.x * 256 + threadIdx.x;
  int row = id >> 7, c = id & 127;
  const float* base = hpart + (size_t)row * 1024 + c * 8;
  f32x4 s0 = *(const f32x4*)(base);
  f32x4 s1 = *(const f32x4*)(base + 4);
#pragma unroll
  for (int ks = 1; ks < 4; ++ks) {
    s0 += *(const f32x4*)(base + (size_t)ks * 2097152);
    s1 += *(const f32x4*)(base + (size_t)ks * 2097152 + 4);
  }
  us8 o;
#pragma unroll
  for (int j = 0; j < 4; ++j) {
    o[j]     = f2h(fast_tanh(s0[j] + b1[c * 8 + j]));
    o[4 + j] = f2h(fast_tanh(s1[j] + b1[c * 8 + 4 + j]));
  }
  char* dst = (char*)hp + ((size_t)(row >> 8) * 32 + (c >> 2)) * 16384
            + (row & 255) * 64 + (((c & 3) ^ ((row >> 1) & 3)) * 16);
  *(us8*)dst = o;
}

// ---------------- spline math (all static indices, per-lane selects) -------

__device__ __forceinline__ void spline_eval(const float* __restrict__ v, float x,
                                            float& phi, float& lt) {
  float w[8], eh[9];
  float wm = v[9];
#pragma unroll
  for (int i = 10; i < 17; ++i) wm = fmaxf(wm, v[i]);
  float wsum = 0.f;
#pragma unroll
  for (int i = 0; i < 8; ++i) { w[i] = __expf(v[9 + i] - wm); wsum += w[i]; }
#pragma unroll
  for (int j = 0; j < 9; ++j) eh[j] = __expf(v[j]);
  float D = 0.f;
#pragma unroll
  for (int i = 0; i < 8; ++i) D += 0.5f * w[i] * (eh[i] + eh[i + 1]);
  float inv_wsum = __builtin_amdgcn_rcpf(wsum);
  float hs = wsum * __builtin_amdgcn_rcpf(D);
  float xw = x * wsum;
  float cum[8];
  float cc = 0.f;
#pragma unroll
  for (int i = 0; i < 8; ++i) { cc += w[i]; cum[i] = cc; }
  int cnt = 0;
#pragma unroll
  for (int i = 0; i < 8; ++i) cnt += (cum[i] < xw) ? 1 : 0;
  int k = min(cnt, 7);
  float wk = 0.f, ehk = 0.f, ehk1 = 0.f, ckm1 = 0.f, pkm1 = 0.f, pp = 0.f;
#pragma unroll
  for (int i = 0; i < 8; ++i) {
    if (i == k) {
      wk = w[i]; ehk = eh[i]; ehk1 = eh[i + 1];
      ckm1 = (i == 0) ? 0.f : cum[i - 1];
      pkm1 = pp;
    }
    pp += 0.5f * w[i] * (eh[i] + eh[i + 1]);
  }
  float wnk = wk * inv_wsum;
  float hk = ehk * hs, hk1 = ehk1 * hs;
  float xkm1 = (k == 0) ? -EPS_C : ckm1 * inv_wsum;
  float phikm1 = pkm1 * inv_wsum * hs;
  float alpha = (x - xkm1) * __builtin_amdgcn_rcpf(wnk);
  phi = phikm1 + alpha * hk * wnk + 0.5f * alpha * alpha * (hk1 - hk) * wnk;
  lt = __logf(hk + alpha * (hk1 - hk));
}

// ---------------- GEMM2 + spline epilogue ----------------------------------
// BM=256, BN=272, BK=32, 8 waves as 4Mx2N (wave tile 64x136, B frags 8/9).
// LDS = max(staging 67.6KB, epi 70.1KB) + b2 = 71.2KB and
// __launch_bounds__(512, 2) [2nd arg = min BLOCKS/CU empirically: VGPR cap
// 131072/1024 = 128 >= our 116] => 2 blocks/CU; co-resident block's MFMA
// hides the per-K-step vmcnt(0) barrier drain.
// Epilogue: 4 passes of 64 rows (waves wr==p write; all waves spline).

__global__ __launch_bounds__(512, 2) void k_gemm2(const unsigned short* __restrict__ hp,
                                                  const unsigned short* __restrict__ w2p,
                                                  const float* __restrict__ b2,
                                                  const float* __restrict__ x_in,
                                                  float* __restrict__ out,
                                                  float* __restrict__ ldpart) {
  __shared__ char sm[71232];                      // staging 2x33792 / epi 70144, +b2 1088
  int tid = threadIdx.x, wid = tid >> 6, l = tid & 63;
  int cl = l & 15, kq = l >> 4;
  int b = blockIdx.x + (blockIdx.y << 3);
  int mt = b & 7;
  int nt = b >> 3;
  int wr = wid >> 1, wc = wid & 1;
  int nf = 8 + wc;                                // B frags: wc=0 -> 8, wc=1 -> 9

  float* b2s = (float*)(sm + 70144);
  if (tid < 272) b2s[tid] = b2[nt * 272 + tid];

  const char* Ab = (const char*)hp + (size_t)(mt * 32) * 16384;
  const char* Bb = (const char*)w2p + (size_t)(nt * 32) * 17408;

  f32x4 acc[4][9] = {};

  auto stage = [&](int i, int buf) {
    char* sA = sm + buf * 33792;
    char* sB = sA + 16384;
    const char* a = Ab + (size_t)i * 16384;
    const char* bb = Bb + (size_t)i * 17408;
    gld16(a + tid * 16, sA + tid * 16);
    gld16(a + 8192 + tid * 16, sA + 8192 + tid * 16);
    gld16(bb + tid * 16, sB + tid * 16);
    gld16(bb + 8192 + tid * 16, sB + 8192 + tid * 16);
    if (tid < 64) gld16(bb + 16384 + tid * 16, sB + 16384 + tid * 16);
  };

  stage(0, 0);
  __syncthreads();

  int swz = (kq * 16) ^ (((cl >> 1) & 3) << 4);
  int aoff = (wr * 64 + cl) * 64 + swz;           // + rf*1024, rf=0..3
  int boff = (wc * 128 + cl) * 64 + swz;          // + cf*1024, cf<nf

  for (int i = 0; i < 32; ++i) {
    if (i + 1 < 32) stage(i + 1, (i + 1) & 1);
    const char* sA = sm + (i & 1) * 33792;
    const char* sB = sA + 16384;
    f16x8 a[4], bfr[9];
#pragma unroll
    for (int rf = 0; rf < 4; ++rf) a[rf] = *(const f16x8*)(sA + aoff + rf * 1024);
#pragma unroll
    for (int cf = 0; cf < 9; ++cf)
      if (cf < nf) bfr[cf] = *(const f16x8*)(sB + boff + cf * 1024);
#pragma unroll
    for (int cf = 0; cf < 9; ++cf)
      if (cf < nf)
#pragma unroll
        for (int rf = 0; rf < 4; ++rf)
          acc[rf][cf] = __builtin_amdgcn_mfma_f32_16x16x32_f16(a[rf], bfr[cf], acc[rf][cf], 0, 0, 0);
    __syncthreads();
  }

  // ---- epilogue: 4 passes of 64 rows through LDS transpose + spline ----
  float* epi = (float*)sm;
  for (int p = 0; p < 4; ++p) {
    if (p) __syncthreads();                       // epi free of prior readers
    if (wr == p) {
#pragma unroll
      for (int rf = 0; rf < 4; ++rf)
#pragma unroll
        for (int cf = 0; cf < 9; ++cf)
          if (cf < nf) {
            int colv = wc * 128 + cf * 16 + cl;
            float bias = b2s[colv];
#pragma unroll
            for (int ri = 0; ri < 4; ++ri) {
              int row = rf * 16 + kq * 4 + ri;
              epi[row * SEPI + colv] = fast_tanh(acc[rf][cf][ri] + bias);
            }
          }
    }
    __syncthreads();

    int row = tid >> 3, si = tid & 7;             // row 0..63, si 0..7
    int grow = mt * 256 + p * 64 + row;
    float lsum = 0.f;
#pragma unroll
    for (int jj = 0; jj < 2; ++jj) {
      int s = si + jj * 8;
      const float* vp = epi + row * SEPI + s * 17;
      float v[17];
#pragma unroll
      for (int j = 0; j < 17; ++j) v[j] = vp[j];
      int sglob = nt * 16 + s;
      float x = x_in[(size_t)grow * 2048 + sglob] * INV_PI;
      float phi, lt;
      spline_eval(v, x, phi, lt);
      out[(size_t)grow * 2048 + sglob] = phi;
      lsum += lt;
    }
    lsum += __shfl_xor(lsum, 1);
    lsum += __shfl_xor(lsum, 2);
    lsum += __shfl_xor(lsum, 4);
    if (si == 0) ldpart[(size_t)nt * 2048 + grow] = lsum;
  }
}

// ---------------- final log-density combine --------------------------------

__global__ void k_ldcombine(const float* __restrict__ ldpart,
                            const float* __restrict__ ld_in,
                            float* __restrict__ out) {
  int b = blockIdx.x * 256 + threadIdx.x;
  float a = 0.f;
  for (int nt = 0; nt < 128; ++nt) a += ldpart[(size_t)nt * 2048 + b];
  out[4194304 + b] = ld_in[b] - a;
}

// ---------------------------------------------------------------------------

extern "C" void kernel_launch(void* const* d_in, const int* in_sizes, int n_in,
                              void* d_out, int out_size, void* d_ws, size_t ws_size,
                              hipStream_t stream) {
  (void)in_sizes; (void)n_in; (void)out_size; (void)ws_size;
  const float* x_in        = (const float*)d_in[0];
  const float* x_passive   = (const float*)d_in[1];
  const float* log_density = (const float*)d_in[2];
  const float* w1          = (const float*)d_in[3];
  const float* b1          = (const float*)d_in[4];
  const float* w2          = (const float*)d_in[5];
  const float* b2          = (const float*)d_in[6];
  float* out = (float*)d_out;
  char* ws = (char*)d_ws;

  float* ms              = (float*)ws;                       // 8 B
  float* redp            = (float*)(ws + 256);               // 16 KB
  unsigned short* xsp    = (unsigned short*)(ws + 65536);    // 8 MB
  unsigned short* w1p    = (unsigned short*)(ws + 8454144);  // 4 MB
  unsigned short* hp     = (unsigned short*)(ws + 12648448); // 4 MB
  float* hpart           = (float*)(ws + 16842752);          // 32 MB
  float* ldpart          = (float*)(ws + 50397184);          // 1 MB
  unsigned short* w2p    = (unsigned short*)(ws + 51445760); // 68 MB

  k_reduce1<<<2048, 256, 0, stream>>>(x_passive, redp);
  k_reduce2<<<1, 256, 0, stream>>>(redp, ms);
  k_pack_xs<<<2048, 256, 0, stream>>>(x_passive, ms, xsp);
  k_pack_w1<<<dim3(4, 64), 256, 0, stream>>>(w1, w1p);
  k_pack_w2<<<dim3(136, 32), 256, 0, stream>>>(w2, w2p);
  k_gemm1<<<dim3(16, 8, 4), 256, 0, stream>>>(xsp, w1p, hpart);
  k_pack_h<<<1024, 256, 0, stream>>>(hpart, b1, hp);
  k_gemm2<<<dim3(8, 128), 512, 0, stream>>>(hp, w2p, b2, x_in, out, ldpart);
  k_ldcombine<<<8, 256, 0, stream>>>(ldpart, log_density, out);
}

// Round 7
// 265.907 us; speedup vs baseline: 1.1513x; 1.1513x over previous
//
#include <hip/hip_runtime.h>

// ---------------------------------------------------------------------------
// QuadraticSplineLayer on MI355X (gfx950)
// reduce(mean/std) -> pack xs/w1/w2 (fp16 swizzled LDS-image blocks)
//   -> GEMM1 (K-split) -> pack_h -> GEMM2+spline epilogue (round-1 structure,
//   B-pinned XCD mapping: all 8 mt-blocks of one nt co-resident on one XCD)
//   -> log-density combine.
// ---------------------------------------------------------------------------

typedef _Float16 f16x8 __attribute__((ext_vector_type(8)));
typedef float    f32x4 __attribute__((ext_vector_type(4)));
typedef unsigned short us8 __attribute__((ext_vector_type(8)));

#define EPS_C   1e-6f
#define INV_PI  0.3183098861837907f
#define SEPI    274                               // padded epi row stride (floats)

__device__ __forceinline__ unsigned short f2h(float f) {
  _Float16 h = (_Float16)f;
  return __builtin_bit_cast(unsigned short, h);
}

__device__ __forceinline__ float fast_tanh(float x) {
  float xc = fminf(fmaxf(x, -15.f), 15.f);
  float p = __expf(2.f * xc);
  return (p - 1.f) * __builtin_amdgcn_rcpf(p + 1.f);
}

__device__ __forceinline__ void gld16(const void* g, void* l) {
  __builtin_amdgcn_global_load_lds(
      (const __attribute__((address_space(1))) unsigned int*)g,
      (__attribute__((address_space(3))) unsigned int*)l, 16, 0, 0);
}

// ---------------- reduction: global mean / rstd of x_passive ---------------

__global__ void k_reduce1(const float* __restrict__ xp, float* __restrict__ part) {
  int tid = threadIdx.x;
  size_t base = (size_t)blockIdx.x * 2048 + (size_t)tid * 8;
  f32x4 v0 = *(const f32x4*)(xp + base);
  f32x4 v1 = *(const f32x4*)(xp + base + 4);
  float s = 0.f, q = 0.f;
#pragma unroll
  for (int j = 0; j < 4; ++j) { s += v0[j] + v1[j]; q += v0[j]*v0[j] + v1[j]*v1[j]; }
#pragma unroll
  for (int o = 32; o; o >>= 1) { s += __shfl_down(s, o); q += __shfl_down(q, o); }
  __shared__ float ls[8];
  int wid = tid >> 6, l = tid & 63;
  if (l == 0) { ls[wid] = s; ls[wid + 4] = q; }
  __syncthreads();
  if (tid == 0) {
    part[blockIdx.x * 2]     = ls[0] + ls[1] + ls[2] + ls[3];
    part[blockIdx.x * 2 + 1] = ls[4] + ls[5] + ls[6] + ls[7];
  }
}

__global__ void k_reduce2(const float* __restrict__ part, float* __restrict__ ms) {
  int tid = threadIdx.x;
  double s = 0.0, q = 0.0;
  for (int i = tid; i < 2048; i += 256) { s += part[2*i]; q += part[2*i+1]; }
#pragma unroll
  for (int o = 32; o; o >>= 1) { s += __shfl_down(s, o); q += __shfl_down(q, o); }
  __shared__ double sd[8];
  if ((tid & 63) == 0) { sd[(tid>>6)*2] = s; sd[(tid>>6)*2+1] = q; }
  __syncthreads();
  if (tid == 0) {
    double S = sd[0]+sd[2]+sd[4]+sd[6], Q = sd[1]+sd[3]+sd[5]+sd[7];
    double N = 4194304.0;
    double mean = S / N;
    double var  = (Q - S*S/N) / (N - 1.0);
    ms[0] = (float)mean;
    ms[1] = (float)(1.0 / sqrt(var));
  }
}

// ---------------- packing kernels (fp16, swizzled LDS-image blocks) --------

__global__ void k_pack_xs(const float* __restrict__ xp, const float* __restrict__ ms,
                          unsigned short* __restrict__ xsp) {
  int b = blockIdx.x, c = threadIdx.x;
  float mean = ms[0], rstd = ms[1];
  const f32x4* src = (const f32x4*)(xp + (size_t)b * 2048 + c * 8);
  f32x4 v0 = src[0], v1 = src[1];
  us8 o;
#pragma unroll
  for (int j = 0; j < 4; ++j) {
    o[j]     = f2h((v0[j] - mean) * rstd);
    o[4 + j] = f2h((v1[j] - mean) * rstd);
  }
  char* dst = (char*)xsp + ((size_t)(b >> 6) * 64 + (c >> 2)) * 4096
            + (b & 63) * 64 + (((c & 3) ^ ((b >> 1) & 3)) * 16);
  *(us8*)dst = o;
}

__global__ void k_pack_w1(const float* __restrict__ w1, unsigned short* __restrict__ w1p) {
  int colg = blockIdx.x * 256 + threadIdx.x;
  int kt = blockIdx.y;
  const float* src = w1 + (size_t)kt * 32 * 1024 + colg;
  float v[32];
#pragma unroll
  for (int kk = 0; kk < 32; ++kk) v[kk] = src[(size_t)kk * 1024];
  int col = colg & 127;
  char* base = (char*)w1p + ((size_t)(colg >> 7) * 64 + kt) * 8192 + col * 64;
#pragma unroll
  for (int c = 0; c < 4; ++c) {
    us8 o;
#pragma unroll
    for (int j = 0; j < 8; ++j) o[j] = f2h(v[c * 8 + j]);
    *(us8*)(base + ((c ^ ((col >> 1) & 3)) * 16)) = o;
  }
}

__global__ void k_pack_w2(const float* __restrict__ w2, unsigned short* __restrict__ w2p) {
  int colg = blockIdx.x * 256 + threadIdx.x;
  int kt = blockIdx.y;
  const float* src = w2 + (size_t)kt * 32 * 34816 + colg;
  float v[32];
#pragma unroll
  for (int kk = 0; kk < 32; ++kk) v[kk] = src[(size_t)kk * 34816];
  int ntile = colg / 272;
  int col = colg - ntile * 272;
  char* base = (char*)w2p + ((size_t)ntile * 32 + kt) * 17408 + col * 64;
#pragma unroll
  for (int c = 0; c < 4; ++c) {
    us8 o;
#pragma unroll
    for (int j = 0; j < 8; ++j) o[j] = f2h(v[c * 8 + j]);
    *(us8*)(base + ((c ^ ((col >> 1) & 3)) * 16)) = o;
  }
}

// ---------------- GEMM1: h_part[ks] = xs @ w1 (K-split, f32 partials) ------

__global__ __launch_bounds__(256) void k_gemm1(const unsigned short* __restrict__ xsp,
                                               const unsigned short* __restrict__ w1p,
                                               float* __restrict__ hpart) {
  __shared__ char sm[2 * 16384];
  int tid = threadIdx.x, wid = tid >> 6, l = tid & 63;
  int cl = l & 15, kq = l >> 4;
  int mt = blockIdx.x, nt = blockIdx.y, ks = blockIdx.z;
  int wr = wid >> 1, wc = wid & 1;

  const char* Ab = (const char*)xsp + ((size_t)(mt * 2) * 64 + ks * 16) * 4096;
  const char* Bb = (const char*)w1p + ((size_t)nt * 64 + ks * 16) * 8192;

  f32x4 acc[4][4] = {};

  auto stage = [&](int i, int buf) {
    char* sA = sm + buf * 16384;
    char* sB = sA + 8192;
    const char* a0 = Ab + (size_t)i * 4096;
    gld16(a0 + tid * 16, sA + tid * 16);
    gld16(a0 + 64 * 4096 + tid * 16, sA + 4096 + tid * 16);
    const char* b0 = Bb + (size_t)i * 8192;
    gld16(b0 + tid * 16, sB + tid * 16);
    gld16(b0 + 4096 + tid * 16, sB + 4096 + tid * 16);
  };

  stage(0, 0);
  __syncthreads();

  int swz = (kq * 16) ^ (((cl >> 1) & 3) << 4);
  int aoff0 = wr * 4096 + cl * 64 + swz;
  int boff0 = (wc * 64 + cl) * 64 + swz;

  for (int i = 0; i < 16; ++i) {
    if (i + 1 < 16) stage(i + 1, (i + 1) & 1);
    const char* sA = sm + (i & 1) * 16384;
    const char* sB = sA + 8192;
    f16x8 a[4], b[4];
#pragma unroll
    for (int rf = 0; rf < 4; ++rf) a[rf] = *(const f16x8*)(sA + aoff0 + rf * 1024);
#pragma unroll
    for (int cf = 0; cf < 4; ++cf) b[cf] = *(const f16x8*)(sB + boff0 + cf * 1024);
#pragma unroll
    for (int rf = 0; rf < 4; ++rf)
#pragma unroll
      for (int cf = 0; cf < 4; ++cf)
        acc[rf][cf] = __builtin_amdgcn_mfma_f32_16x16x32_f16(a[rf], b[cf], acc[rf][cf], 0, 0, 0);
    __syncthreads();
  }

  float* dst = hpart + (size_t)ks * 2048 * 1024;
#pragma unroll
  for (int rf = 0; rf < 4; ++rf)
#pragma unroll
    for (int cf = 0; cf < 4; ++cf)
#pragma unroll
      for (int ri = 0; ri < 4; ++ri) {
        int row = mt * 128 + wr * 64 + rf * 16 + kq * 4 + ri;
        int col = nt * 128 + wc * 64 + cf * 16 + cl;
        dst[(size_t)row * 1024 + col] = acc[rf][cf][ri];
      }
}

// ---------------- pack_h: sum K-split partials, +b1, tanh, fp16 pack -------

__global__ void k_pack_h(const float* __restrict__ hpart, const float* __restrict__ b1,
                         unsigned short* __restrict__ hp) {
  int id = blockIdx.x * 256 + threadIdx.x;
  int row = id >> 7, c = id & 127;
  const float* base = hpart + (size_t)row * 1024 + c * 8;
  f32x4 s0 = *(const f32x4*)(base);
  f32x4 s1 = *(const f32x4*)(base + 4);
#pragma unroll
  for (int ks = 1; ks < 4; ++ks) {
    s0 += *(const f32x4*)(base + (size_t)ks * 2097152);
    s1 += *(const f32x4*)(base + (size_t)ks * 2097152 + 4);
  }
  us8 o;
#pragma unroll
  for (int j = 0; j < 4; ++j) {
    o[j]     = f2h(fast_tanh(s0[j] + b1[c * 8 + j]));
    o[4 + j] = f2h(fast_tanh(s1[j] + b1[c * 8 + 4 + j]));
  }
  char* dst = (char*)hp + ((size_t)(row >> 8) * 32 + (c >> 2)) * 16384
            + (row & 255) * 64 + (((c & 3) ^ ((row >> 1) & 3)) * 16);
  *(us8*)dst = o;
}

// ---------------- spline math (all static indices, per-lane selects) -------

__device__ __forceinline__ void spline_eval(const float* __restrict__ v, float x,
                                            float& phi, float& lt) {
  float w[8], eh[9];
  float wm = v[9];
#pragma unroll
  for (int i = 10; i < 17; ++i) wm = fmaxf(wm, v[i]);
  float wsum = 0.f;
#pragma unroll
  for (int i = 0; i < 8; ++i) { w[i] = __expf(v[9 + i] - wm); wsum += w[i]; }
#pragma unroll
  for (int j = 0; j < 9; ++j) eh[j] = __expf(v[j]);
  float D = 0.f;
#pragma unroll
  for (int i = 0; i < 8; ++i) D += 0.5f * w[i] * (eh[i] + eh[i + 1]);
  float inv_wsum = __builtin_amdgcn_rcpf(wsum);
  float hs = wsum * __builtin_amdgcn_rcpf(D);
  float xw = x * wsum;
  float cum[8];
  float cc = 0.f;
#pragma unroll
  for (int i = 0; i < 8; ++i) { cc += w[i]; cum[i] = cc; }
  int cnt = 0;
#pragma unroll
  for (int i = 0; i < 8; ++i) cnt += (cum[i] < xw) ? 1 : 0;
  int k = min(cnt, 7);
  float wk = 0.f, ehk = 0.f, ehk1 = 0.f, ckm1 = 0.f, pkm1 = 0.f, pp = 0.f;
#pragma unroll
  for (int i = 0; i < 8; ++i) {
    if (i == k) {
      wk = w[i]; ehk = eh[i]; ehk1 = eh[i + 1];
      ckm1 = (i == 0) ? 0.f : cum[i - 1];
      pkm1 = pp;
    }
    pp += 0.5f * w[i] * (eh[i] + eh[i + 1]);
  }
  float wnk = wk * inv_wsum;
  float hk = ehk * hs, hk1 = ehk1 * hs;
  float xkm1 = (k == 0) ? -EPS_C : ckm1 * inv_wsum;
  float phikm1 = pkm1 * inv_wsum * hs;
  float alpha = (x - xkm1) * __builtin_amdgcn_rcpf(wnk);
  phi = phikm1 + alpha * hk * wnk + 0.5f * alpha * alpha * (hk1 - hk) * wnk;
  lt = __logf(hk + alpha * (hk1 - hk));
}

// ---------------- GEMM2 + spline epilogue ----------------------------------
// BM=256, BN=272 (16 s-groups), BK=32, 8 waves, wave tile 32x272.
// Round-1 proven loop (2-buffer, __syncthreads). B-pinned XCD mapping:
// XCD = b%8 (HW round-robin); j=b>>3 is the per-XCD sequence; mt=j&7,
// nt=xcd*16+(j>>3). The 32-block/XCD resident window = 4 nt x all 8 mt,
// so each B-tile is HBM-fetched once and L2-served to the other 7 blocks;
// the whole A (4 MB fp16) is L2-resident per XCD.

__global__ __launch_bounds__(512) void k_gemm2(const unsigned short* __restrict__ hp,
                                               const unsigned short* __restrict__ w2p,
                                               const float* __restrict__ b2,
                                               const float* __restrict__ x_in,
                                               float* __restrict__ out,
                                               float* __restrict__ ldpart) {
  __shared__ char sm[141376];                     // staging 2x33792 / epi 140288, +b2 1088
  int tid = threadIdx.x, wid = tid >> 6, l = tid & 63;
  int cl = l & 15, kq = l >> 4;
  int b = blockIdx.x + (blockIdx.y << 3);
  int xcd = b & 7;
  int j = b >> 3;
  int mt = j & 7;
  int nt = xcd * 16 + (j >> 3);

  float* b2s = (float*)(sm + 140288);
  if (tid < 272) b2s[tid] = b2[nt * 272 + tid];

  const char* Ab = (const char*)hp + (size_t)(mt * 32) * 16384;
  const char* Bb = (const char*)w2p + (size_t)(nt * 32) * 17408;

  f32x4 acc[2][17] = {};

  auto stage = [&](int i, int buf) {
    char* sA = sm + buf * 33792;
    char* sB = sA + 16384;
    const char* a = Ab + (size_t)i * 16384;
    const char* bb = Bb + (size_t)i * 17408;
    gld16(a + tid * 16, sA + tid * 16);
    gld16(a + 8192 + tid * 16, sA + 8192 + tid * 16);
    gld16(bb + tid * 16, sB + tid * 16);
    gld16(bb + 8192 + tid * 16, sB + 8192 + tid * 16);
    if (tid < 64) gld16(bb + 16384 + tid * 16, sB + 16384 + tid * 16);
  };

  stage(0, 0);
  __syncthreads();

  int swz = (kq * 16) ^ (((cl >> 1) & 3) << 4);
  int aoff = (wid * 32 + cl) * 64 + swz;
  int boff = cl * 64 + swz;

  for (int i = 0; i < 32; ++i) {
    if (i + 1 < 32) stage(i + 1, (i + 1) & 1);
    const char* sA = sm + (i & 1) * 33792;
    const char* sB = sA + 16384;
    f16x8 a0 = *(const f16x8*)(sA + aoff);
    f16x8 a1 = *(const f16x8*)(sA + aoff + 1024);
#pragma unroll
    for (int f = 0; f < 17; ++f) {
      f16x8 bf = *(const f16x8*)(sB + boff + f * 1024);
      acc[0][f] = __builtin_amdgcn_mfma_f32_16x16x32_f16(a0, bf, acc[0][f], 0, 0, 0);
      acc[1][f] = __builtin_amdgcn_mfma_f32_16x16x32_f16(a1, bf, acc[1][f], 0, 0, 0);
    }
    __syncthreads();
  }

  // ---- epilogue: 2 passes of 128 rows through LDS transpose + spline ----
  float* epi = (float*)sm;
  for (int pass = 0; pass < 2; ++pass) {
    if (pass) __syncthreads();                    // epi free of prior readers
    if ((wid >> 2) == pass) {
      int rbase = (wid & 3) * 32;
#pragma unroll
      for (int r = 0; r < 2; ++r)
#pragma unroll
        for (int f = 0; f < 17; ++f) {
          int colv = f * 16 + cl;
          float bias = b2s[colv];
#pragma unroll
          for (int ri = 0; ri < 4; ++ri) {
            int row = rbase + r * 16 + kq * 4 + ri;
            epi[row * SEPI + colv] = fast_tanh(acc[r][f][ri] + bias);
          }
        }
    }
    __syncthreads();

    int row = tid >> 2;                           // 0..127
    int grow = mt * 256 + pass * 128 + row;
    float lsum = 0.f;
#pragma unroll
    for (int jj = 0; jj < 4; ++jj) {
      int s = (tid & 3) + jj * 4;                 // 0..15
      const float* vp = epi + row * SEPI + s * 17;
      float v[17];
#pragma unroll
      for (int jv = 0; jv < 17; ++jv) v[jv] = vp[jv];
      int sglob = nt * 16 + s;
      float x = x_in[(size_t)grow * 2048 + sglob] * INV_PI;
      float phi, lt;
      spline_eval(v, x, phi, lt);
      out[(size_t)grow * 2048 + sglob] = phi;
      lsum += lt;
    }
    lsum += __shfl_xor(lsum, 1);
    lsum += __shfl_xor(lsum, 2);
    if ((tid & 3) == 0) ldpart[(size_t)nt * 2048 + grow] = lsum;
    __syncthreads();
  }
}

// ---------------- final log-density combine --------------------------------

__global__ void k_ldcombine(const float* __restrict__ ldpart,
                            const float* __restrict__ ld_in,
                            float* __restrict__ out) {
  int b = blockIdx.x * 256 + threadIdx.x;
  float a = 0.f;
  for (int nt = 0; nt < 128; ++nt) a += ldpart[(size_t)nt * 2048 + b];
  out[4194304 + b] = ld_in[b] - a;
}

// ---------------------------------------------------------------------------

extern "C" void kernel_launch(void* const* d_in, const int* in_sizes, int n_in,
                              void* d_out, int out_size, void* d_ws, size_t ws_size,
                              hipStream_t stream) {
  (void)in_sizes; (void)n_in; (void)out_size; (void)ws_size;
  const float* x_in        = (const float*)d_in[0];
  const float* x_passive   = (const float*)d_in[1];
  const float* log_density = (const float*)d_in[2];
  const float* w1          = (const float*)d_in[3];
  const float* b1          = (const float*)d_in[4];
  const float* w2          = (const float*)d_in[5];
  const float* b2          = (const float*)d_in[6];
  float* out = (float*)d_out;
  char* ws = (char*)d_ws;

  float* ms              = (float*)ws;                       // 8 B
  float* redp            = (float*)(ws + 256);               // 16 KB
  unsigned short* xsp    = (unsigned short*)(ws + 65536);    // 8 MB
  unsigned short* w1p    = (unsigned short*)(ws + 8454144);  // 4 MB
  unsigned short* hp     = (unsigned short*)(ws + 12648448); // 4 MB
  float* hpart           = (float*)(ws + 16842752);          // 32 MB
  float* ldpart          = (float*)(ws + 50397184);          // 1 MB
  unsigned short* w2p    = (unsigned short*)(ws + 51445760); // 68 MB

  k_reduce1<<<2048, 256, 0, stream>>>(x_passive, redp);
  k_reduce2<<<1, 256, 0, stream>>>(redp, ms);
  k_pack_xs<<<2048, 256, 0, stream>>>(x_passive, ms, xsp);
  k_pack_w1<<<dim3(4, 64), 256, 0, stream>>>(w1, w1p);
  k_pack_w2<<<dim3(136, 32), 256, 0, stream>>>(w2, w2p);
  k_gemm1<<<dim3(16, 8, 4), 256, 0, stream>>>(xsp, w1p, hpart);
  k_pack_h<<<1024, 256, 0, stream>>>(hpart, b1, hp);
  k_gemm2<<<dim3(8, 128), 512, 0, stream>>>(hp, w2p, b2, x_in, out, ldpart);
  k_ldcombine<<<8, 256, 0, stream>>>(ldpart, log_density, out);
}